// Round 13
// baseline (365.286 us; speedup 1.0000x reference)
//
#include <hip/hip_runtime.h>
#include <hip/hip_bf16.h>

#define S_ 4
#define B_ 256
#define L_ 256
#define D_ 512
#define NQ_ 4
#define H_ 2048
#define G_ 3072

typedef __attribute__((ext_vector_type(4))) float f32x4;
typedef __attribute__((ext_vector_type(8))) short s16x8;

__device__ __forceinline__ unsigned short f2bf(float x) {
    __hip_bfloat16 hb = __float2bfloat16(x);
    return reinterpret_cast<unsigned short&>(hb);
}

__device__ __forceinline__ f32x4 ntload4(const float* p) {
    return __builtin_nontemporal_load(reinterpret_cast<const f32x4*>(p));
}

__device__ __forceinline__ void gll16(const void* g, void* l) {
    __builtin_amdgcn_global_load_lds(
        (const __attribute__((address_space(1))) unsigned int*)g,
        (__attribute__((address_space(3))) unsigned int*)l, 16, 0, 0);
}

__device__ __forceinline__ float block_sum256(float v, float* red) {
    #pragma unroll
    for (int off = 32; off > 0; off >>= 1) v += __shfl_down(v, off, 64);
    int tid = threadIdx.x;
    int lane = tid & 63, wid = tid >> 6;
    if (lane == 0) red[wid] = v;
    __syncthreads();
    float r = (tid < 4) ? red[tid] : 0.f;
    #pragma unroll
    for (int off = 4; off > 0; off >>= 1) r += __shfl_down(r, off, 64);
    if (tid == 0) red[0] = r;
    __syncthreads();
    float out = red[0];
    __syncthreads();
    return out;
}

// ---------------- kernel 1: prep -- A_ns = bf16(ns*gamma), per-b ns sums ----------------
__global__ __launch_bounds__(256) void prep_kernel(
    const float* __restrict__ ns_tokens,     // (B, 2048)
    const float* __restrict__ gin_gamma,     // (G)
    __hip_bfloat16* __restrict__ A_ns,       // (B, 2048)
    float* __restrict__ nssum)               // (B, 2) {sum, sumsq}
{
    const int b = blockIdx.x;
    const int tid = threadIdx.x;
    __shared__ float red[8];
    float s1 = 0.f, s2 = 0.f;
    #pragma unroll
    for (int k = 0; k < 8; ++k) {
        int g = tid + k * 256;
        float v = ns_tokens[(size_t)b * 2048 + g];
        s1 += v; s2 += v * v;
        A_ns[(size_t)b * 2048 + g] = __float2bfloat16(v * gin_gamma[g]);
    }
    s1 = block_sum256(s1, red);
    s2 = block_sum256(s2, red);
    if (tid == 0) { nssum[b * 2] = s1; nssum[b * 2 + 1] = s2; }
}

// ---------------- kernel 2: MEGA v2 -- pool || P-gemm, INTERLEAVED roles, 40 KB LDS ---------
// r12 failed because 80 KB LDS -> 1 block/CU (pool lost TLP) and block-ordered roles ran
// serially. v2: 40 KB LDS (P-gemm single-buffered As 32K + Ws 8K, 2-barrier loop) and
// bid%3 interleave -> every CU hosts ~2:1 pool:gemm; both HBM streams share the pipe.
__global__ __launch_bounds__(256) void mega_kernel(
    const float* __restrict__ seq_tokens,
    const unsigned char* __restrict__ masks_raw,
    const __hip_bfloat16* __restrict__ A_ns,
    const float* __restrict__ W1,
    const float* __restrict__ gin_gamma,
    const float* __restrict__ gin_beta,
    float* __restrict__ pooled,              // (S,B,D)
    float* __restrict__ Pbuf,                // (16, 256, 2048) f32
    float* __restrict__ uprime,              // (16, 2048)
    float* __restrict__ usec)                // (16, 2048)
{
    __shared__ __align__(16) char smem[40960];

    const int bid = blockIdx.x;          // 0..1535
    const int g3 = bid / 3, r3 = bid % 3;

    if (r3 != 2) {
        // ================= pool role (sb = 2*g3 + r3, 0..1023) =================
        const int sb = 2 * g3 + r3;
        const int tid = threadIdx.x;
        f32x4* spart = reinterpret_cast<f32x4*>(smem);            // 4 KB
        float* sval  = reinterpret_cast<float*>(smem + 4096);     // 1 KB
        float* scount = reinterpret_cast<float*>(smem + 5120);    // 16 B
        int* is_bool_flag = reinterpret_cast<int*>(smem + 5184);

        if (tid == 0) *is_bool_flag = 0;
        __syncthreads();
        {
            unsigned int w = reinterpret_cast<const unsigned int*>(masks_raw)[tid];
            if (w & 0xFFFFFF00u) *is_bool_flag = 1;
        }
        __syncthreads();
        const bool is_bool = (*is_bool_flag != 0);

        int mval;
        if (is_bool) mval = masks_raw[(size_t)sb * L_ + tid];
        else         mval = reinterpret_cast<const int*>(masks_raw)[(size_t)sb * L_ + tid];
        float valid = mval ? 0.f : 1.f;
        sval[tid] = valid;
        float c = valid;
        #pragma unroll
        for (int off = 32; off > 0; off >>= 1) c += __shfl_down(c, off, 64);
        if ((tid & 63) == 0) scount[tid >> 6] = c;
        __syncthreads();
        const float denom = fmaxf(scount[0] + scount[1] + scount[2] + scount[3], 1.f);

        const float* base = seq_tokens + (size_t)sb * L_ * D_;
        const int cidx = tid & 127;
        const int rg = tid >> 7;
        f32x4 acc = {0.f, 0.f, 0.f, 0.f};
        for (int l = rg; l < L_; l += 2) {
            float vl = sval[l];
            f32x4 v = *reinterpret_cast<const f32x4*>(base + (size_t)l * D_ + cidx * 4);
            acc += v * vl;
        }
        spart[tid] = acc;
        __syncthreads();
        if (tid < 128) {
            f32x4 r = spart[tid] + spart[tid + 128];
            r *= (1.f / denom);
            *reinterpret_cast<f32x4*>(pooled + (size_t)sb * D_ + cidx * 4) = r;
        }
        return;
    }

    // ================= P-gemm role (p = g3, 0..511) =================
    const int p = g3;
    const int wg = (p & 7) * 64 + (p >> 3);
    const int ntile = wg & 31;      // 0..31
    const int sq = wg >> 5;         // 0..15
    const int tid = threadIdx.x;
    const int lane = tid & 63;
    const int wid = tid >> 6;

    unsigned short* As = reinterpret_cast<unsigned short*>(smem);           // 256x64 = 32 KB
    unsigned short* Ws = reinterpret_cast<unsigned short*>(smem + 65536 / 2); // 64x64 = 8 KB

    const char* Ag = reinterpret_cast<const char*>(A_ns);   // (256, 2048) bf16, shared
    const float* Wb = W1 + (size_t)sq * G_ * H_ + ntile * 64;

    f32x4 acc[4][4];
    #pragma unroll
    for (int i = 0; i < 4; ++i)
        #pragma unroll
        for (int j = 0; j < 4; ++j) acc[i][j] = (f32x4){0.f, 0.f, 0.f, 0.f};
    float upp[4] = {0.f, 0.f, 0.f, 0.f};
    float usp[4] = {0.f, 0.f, 0.f, 0.f};

    unsigned aoff[8];
    #pragma unroll
    for (int i = 0; i < 8; ++i) {
        int row = wid * 64 + i * 8 + (lane >> 3);
        int swz = ((lane >> 3) ^ i) & 7;
        aoff[i] = (unsigned)row * 4096 + (((lane & 7) ^ swz) * 16);
    }

    const int wn0 = (tid & 15) * 4;
    const int wk0 = (tid >> 4) * 4;
    unsigned offW[4];
    #pragma unroll
    for (int nn = 0; nn < 4; ++nn) {
        int row = wn0 + nn;
        int swz = (row ^ (row >> 3)) & 7;
        offW[nn] = (unsigned)((row * 128 + wk0 * 2) ^ (swz << 4));
    }
    unsigned offA[2][4], offB[2][4];
    #pragma unroll
    for (int kb = 0; kb < 2; ++kb) {
        #pragma unroll
        for (int mi = 0; mi < 4; ++mi) {
            int r = wid * 64 + mi * 16 + (lane & 15);
            int swz = (r ^ (r >> 3)) & 7;
            offA[kb][mi] = r * 128 + ((((lane >> 4) + kb * 4) ^ swz) * 16);
        }
        #pragma unroll
        for (int ni = 0; ni < 4; ++ni) {
            int r = ni * 16 + (lane & 15);
            int swz = (r ^ (r >> 3)) & 7;
            offB[kb][ni] = r * 128 + ((((lane >> 4) + kb * 4) ^ swz) * 16);
        }
    }

    // ---- main loop: 32 K-steps (K=2048), 2-barrier single-buffer
    for (int kt = 0; kt < 32; ++kt) {
        __syncthreads();   // [S1] prev-step MFMA reads retired
        // W(kt) -> regs (nt) + gamma/beta
        f32x4 gq = *reinterpret_cast<const f32x4*>(gin_gamma + kt * 64 + wk0);
        f32x4 bq = *reinterpret_cast<const f32x4*>(gin_beta + kt * 64 + wk0);
        f32x4 wreg[4];
        {
            const float* wp = Wb + (size_t)(kt * 64 + wk0) * H_ + wn0;
            #pragma unroll
            for (int kk = 0; kk < 4; ++kk)
                wreg[kk] = ntload4(wp + (size_t)kk * H_);
        }
        // gll A(kt) -> As
        {
            const unsigned kbyte = (unsigned)kt * 128;
            #pragma unroll
            for (int i = 0; i < 8; ++i)
                gll16(Ag + (aoff[i] + kbyte), reinterpret_cast<char*>(As) + (wid * 64 + i * 8) * 128);
        }
        // pack W -> Ws + u'/u'' FMA
        #pragma unroll
        for (int nn = 0; nn < 4; ++nn) {
            unsigned long long pk =
                (unsigned long long)f2bf(wreg[0][nn]) |
                ((unsigned long long)f2bf(wreg[1][nn]) << 16) |
                ((unsigned long long)f2bf(wreg[2][nn]) << 32) |
                ((unsigned long long)f2bf(wreg[3][nn]) << 48);
            *reinterpret_cast<unsigned long long*>(reinterpret_cast<char*>(Ws) + offW[nn]) = pk;
        }
        #pragma unroll
        for (int kk = 0; kk < 4; ++kk)
            #pragma unroll
            for (int j = 0; j < 4; ++j) {
                upp[j] += gq[kk] * wreg[kk][j];
                usp[j] += bq[kk] * wreg[kk][j];
            }
        __syncthreads();   // [S2] drains gll (vmcnt) + ds_write (lgkm): As/Ws ready

        const char* Al = reinterpret_cast<const char*>(As);
        const char* Wl = reinterpret_cast<const char*>(Ws);
        #pragma unroll
        for (int kb = 0; kb < 2; ++kb) {
            s16x8 af[4], bfr[4];
            #pragma unroll
            for (int mi = 0; mi < 4; ++mi)
                af[mi] = *reinterpret_cast<const s16x8*>(Al + offA[kb][mi]);
            #pragma unroll
            for (int ni = 0; ni < 4; ++ni)
                bfr[ni] = *reinterpret_cast<const s16x8*>(Wl + offB[kb][ni]);
            #pragma unroll
            for (int mi = 0; mi < 4; ++mi)
                #pragma unroll
                for (int ni = 0; ni < 4; ++ni)
                    acc[mi][ni] = __builtin_amdgcn_mfma_f32_16x16x32_bf16(af[mi], bfr[ni], acc[mi][ni], 0, 0, 0);
        }
    }

    // ---- epilogue: write P (raw acc), reduce u'/u'' across wk0 groups
    float* Pd = Pbuf + (size_t)sq * 524288;
    #pragma unroll
    for (int mi = 0; mi < 4; ++mi)
        #pragma unroll
        for (int ni = 0; ni < 4; ++ni)
            #pragma unroll
            for (int r = 0; r < 4; ++r) {
                int row = wid * 64 + mi * 16 + ((lane >> 4) << 2) + r;
                int col = ntile * 64 + ni * 16 + (lane & 15);
                Pd[(size_t)row * 2048 + col] = acc[mi][ni][r];
            }
    __syncthreads();
    float* red2 = reinterpret_cast<float*>(smem);   // [16][64] u' then [16][64] u'' (8 KB)
    #pragma unroll
    for (int j = 0; j < 4; ++j) {
        red2[(tid >> 4) * 64 + wn0 + j] = upp[j];
        red2[1024 + (tid >> 4) * 64 + wn0 + j] = usp[j];
    }
    __syncthreads();
    if (tid < 64) {
        float su = 0.f, ss = 0.f;
        #pragma unroll
        for (int k = 0; k < 16; ++k) {
            su += red2[k * 64 + tid];
            ss += red2[1024 + k * 64 + tid];
        }
        uprime[sq * 2048 + ntile * 64 + tid] = su;
        usec[sq * 2048 + ntile * 64 + tid] = ss;
    }
}

// ---------------- kernel 3: tailprep -- stat LN, group-LN stats (mu,rinv), gi_tail ----------
__global__ __launch_bounds__(256) void tailprep_kernel(
    const float* __restrict__ seq_stats,
    const float* __restrict__ stat_W,
    const float* __restrict__ stat_b,
    const float* __restrict__ stat_ln_g,
    const float* __restrict__ stat_ln_b,
    const float* __restrict__ gin_gamma,
    const float* __restrict__ gin_beta,
    const float* __restrict__ pooled,        // (S,B,D)
    const float* __restrict__ nssum,         // (B,2)
    float* __restrict__ musig,               // (S*B, 2)
    __hip_bfloat16* __restrict__ gi_tail)    // (S,B,1024)
{
    const int sb = blockIdx.x;
    const int s = sb >> 8;
    const int b = sb & 255;
    const int tid = threadIdx.x;
    __shared__ float red[8];

    float st[6];
    #pragma unroll
    for (int f = 0; f < 6; ++f) st[f] = seq_stats[(size_t)sb * 6 + f];

    float sp[2];
    #pragma unroll
    for (int k = 0; k < 2; ++k) {
        int d = tid + k * 256;
        float a = stat_b[s * D_ + d];
        #pragma unroll
        for (int f = 0; f < 6; ++f) a += st[f] * stat_W[(s * 6 + f) * D_ + d];
        sp[k] = a;
    }
    float ssum = block_sum256(sp[0] + sp[1], red);
    float ssq  = block_sum256(sp[0] * sp[0] + sp[1] * sp[1], red);
    float mu_s = ssum / D_;
    float var_s = ssq / D_ - mu_s * mu_s;
    float ri_s = rsqrtf(var_s + 1e-5f);
    float stn[2];
    #pragma unroll
    for (int k = 0; k < 2; ++k) {
        int d = tid + k * 256;
        stn[k] = (sp[k] - mu_s) * ri_s * stat_ln_g[s * D_ + d] + stat_ln_b[s * D_ + d];
    }

    float pv[2];
    #pragma unroll
    for (int k = 0; k < 2; ++k)
        pv[k] = pooled[(size_t)sb * D_ + tid + k * 256];

    float pS1 = block_sum256(pv[0] + pv[1], red);
    float pS2 = block_sum256(pv[0] * pv[0] + pv[1] * pv[1], red);
    float tS1 = block_sum256(stn[0] + stn[1], red);
    float tS2 = block_sum256(stn[0] * stn[0] + stn[1] * stn[1], red);

    float mu = (nssum[b * 2] + pS1 + tS1) / G_;
    float e2 = (nssum[b * 2 + 1] + pS2 + tS2) / G_;
    float rinv = rsqrtf(e2 - mu * mu + 1e-5f);
    if (tid == 0) { musig[sb * 2] = mu; musig[sb * 2 + 1] = rinv; }

    #pragma unroll
    for (int k = 0; k < 2; ++k) {
        int d = tid + k * 256;
        float o = (pv[k] - mu) * rinv * gin_gamma[2048 + d] + gin_beta[2048 + d];
        gi_tail[(size_t)sb * 1024 + d] = __float2bfloat16(o);
        float o2 = (stn[k] - mu) * rinv * gin_gamma[2560 + d] + gin_beta[2560 + d];
        gi_tail[(size_t)sb * 1024 + 512 + d] = __float2bfloat16(o2);
    }
}

// ---------------- kernel 4: tail-gemm -- K=1024 tail product + merge + silu -> h ------------
__global__ __launch_bounds__(256) void tailgemm_kernel(
    const __hip_bfloat16* __restrict__ gi_tail,  // (S,B,1024)
    const float* __restrict__ W1,
    const float* __restrict__ b1,
    const float* __restrict__ Pbuf,
    const float* __restrict__ uprime,
    const float* __restrict__ usec,
    const float* __restrict__ musig,
    __hip_bfloat16* __restrict__ hbuf)           // (S*Nq, B, H)
{
    const int bid = blockIdx.x;
    const int wg = (bid & 7) * 64 + (bid >> 3);
    const int ntile = wg & 31;
    const int sq = wg >> 5;
    const int s = sq >> 2;
    const int tid = threadIdx.x;
    const int lane = tid & 63;
    const int wid = tid >> 6;

    __shared__ __align__(16) unsigned short As[2][256 * 64];
    __shared__ __align__(16) unsigned short Ws[2][64 * 64];

    const char* Ag = reinterpret_cast<const char*>(gi_tail) + (size_t)s * 524288;
    const float* Wb = W1 + (size_t)sq * G_ * H_ + (size_t)2048 * H_ + ntile * 64;

    f32x4 acc[4][4];
    #pragma unroll
    for (int i = 0; i < 4; ++i)
        #pragma unroll
        for (int j = 0; j < 4; ++j) acc[i][j] = (f32x4){0.f, 0.f, 0.f, 0.f};

    unsigned aoff[8];
    #pragma unroll
    for (int i = 0; i < 8; ++i) {
        int row = wid * 64 + i * 8 + (lane >> 3);
        int swz = ((lane >> 3) ^ i) & 7;
        aoff[i] = (unsigned)row * 2048 + (((lane & 7) ^ swz) * 16);
    }
    const int wn0 = (tid & 15) * 4;
    const int wk0 = (tid >> 4) * 4;
    unsigned offW[4];
    #pragma unroll
    for (int nn = 0; nn < 4; ++nn) {
        int row = wn0 + nn;
        int swz = (row ^ (row >> 3)) & 7;
        offW[nn] = (unsigned)((row * 128 + wk0 * 2) ^ (swz << 4));
    }
    unsigned offA[2][4], offB[2][4];
    #pragma unroll
    for (int kb = 0; kb < 2; ++kb) {
        #pragma unroll
        for (int mi = 0; mi < 4; ++mi) {
            int r = wid * 64 + mi * 16 + (lane & 15);
            int swz = (r ^ (r >> 3)) & 7;
            offA[kb][mi] = r * 128 + ((((lane >> 4) + kb * 4) ^ swz) * 16);
        }
        #pragma unroll
        for (int ni = 0; ni < 4; ++ni) {
            int r = ni * 16 + (lane & 15);
            int swz = (r ^ (r >> 3)) & 7;
            offB[kb][ni] = r * 128 + ((((lane >> 4) + kb * 4) ^ swz) * 16);
        }
    }

    {
        char* dst = reinterpret_cast<char*>(&As[0][0]);
        #pragma unroll
        for (int i = 0; i < 8; ++i)
            gll16(Ag + aoff[i], dst + (wid * 64 + i * 8) * 128);
        f32x4 w0[4];
        #pragma unroll
        for (int kk = 0; kk < 4; ++kk)
            w0[kk] = ntload4(Wb + (size_t)(wk0 + kk) * H_ + wn0);
        #pragma unroll
        for (int nn = 0; nn < 4; ++nn) {
            unsigned long long pk =
                (unsigned long long)f2bf(w0[0][nn]) |
                ((unsigned long long)f2bf(w0[1][nn]) << 16) |
                ((unsigned long long)f2bf(w0[2][nn]) << 32) |
                ((unsigned long long)f2bf(w0[3][nn]) << 48);
            *reinterpret_cast<unsigned long long*>(reinterpret_cast<char*>(&Ws[0][0]) + offW[nn]) = pk;
        }
        asm volatile("s_waitcnt lgkmcnt(0)" ::: "memory");
        __builtin_amdgcn_s_barrier();
    }

    for (int kt = 0; kt < 16; ++kt) {
        const int cur = kt & 1, nxt = cur ^ 1;
        const int kn = (kt < 15) ? kt + 1 : 15;

        f32x4 wreg[4];
        {
            const float* wp = Wb + (size_t)(kn * 64 + wk0) * H_ + wn0;
            #pragma unroll
            for (int kk = 0; kk < 4; ++kk)
                wreg[kk] = ntload4(wp + (size_t)kk * H_);
        }
        {
            char* dst = reinterpret_cast<char*>(&As[nxt][0]);
            const unsigned kbyte = (unsigned)kn * 128;
            #pragma unroll
            for (int i = 0; i < 8; ++i)
                gll16(Ag + (aoff[i] + kbyte), dst + (wid * 64 + i * 8) * 128);
        }
        asm volatile("s_waitcnt vmcnt(12)" ::: "memory");
        __builtin_amdgcn_sched_barrier(0);

        const char* Al = reinterpret_cast<const char*>(&As[cur][0]);
        const char* Wl = reinterpret_cast<const char*>(&Ws[cur][0]);
        #pragma unroll
        for (int kb = 0; kb < 2; ++kb) {
            s16x8 af[4], bfr[4];
            #pragma unroll
            for (int mi = 0; mi < 4; ++mi)
                af[mi] = *reinterpret_cast<const s16x8*>(Al + offA[kb][mi]);
            #pragma unroll
            for (int ni = 0; ni < 4; ++ni)
                bfr[ni] = *reinterpret_cast<const s16x8*>(Wl + offB[kb][ni]);
            #pragma unroll
            for (int mi = 0; mi < 4; ++mi)
                #pragma unroll
                for (int ni = 0; ni < 4; ++ni)
                    acc[mi][ni] = __builtin_amdgcn_mfma_f32_16x16x32_bf16(af[mi], bfr[ni], acc[mi][ni], 0, 0, 0);
        }

        #pragma unroll
        for (int nn = 0; nn < 4; ++nn) {
            unsigned long long pk =
                (unsigned long long)f2bf(wreg[0][nn]) |
                ((unsigned long long)f2bf(wreg[1][nn]) << 16) |
                ((unsigned long long)f2bf(wreg[2][nn]) << 32) |
                ((unsigned long long)f2bf(wreg[3][nn]) << 48);
            *reinterpret_cast<unsigned long long*>(reinterpret_cast<char*>(&Ws[nxt][0]) + offW[nn]) = pk;
        }
        asm volatile("s_waitcnt lgkmcnt(0)" ::: "memory");
        __builtin_amdgcn_s_barrier();
    }

    // ---- epilogue: h = silu(rinv*(P - mu*u') + u'' + T + b1)
    const float* b1p = b1 + (size_t)sq * H_ + ntile * 64;
    const float* Pd = Pbuf + (size_t)sq * 524288;
    __hip_bfloat16* hp = hbuf + (size_t)sq * B_ * H_;
    #pragma unroll
    for (int ni = 0; ni < 4; ++ni) {
        int coll = ni * 16 + (lane & 15);
        float up = uprime[sq * 2048 + ntile * 64 + coll];
        float us = usec[sq * 2048 + ntile * 64 + coll];
        float bb = b1p[coll];
        #pragma unroll
        for (int mi = 0; mi < 4; ++mi)
            #pragma unroll
            for (int r = 0; r < 4; ++r) {
                int row = wid * 64 + mi * 16 + ((lane >> 4) << 2) + r;
                float mu_ = musig[(s * 256 + row) * 2];
                float ri_ = musig[(s * 256 + row) * 2 + 1];
                float Pv = Pd[(size_t)row * 2048 + ntile * 64 + coll];
                float x = ri_ * (Pv - mu_ * up) + us + acc[mi][ni][r] + bb;
                float sg = 1.f / (1.f + __expf(-x));
                hp[(size_t)row * H_ + ntile * 64 + coll] = __float2bfloat16(x * sg);
            }
    }
}

// ---------------- kernel 5: GEMM2 (r11 exact) ----------------
__global__ __launch_bounds__(256, 4) void gemm2_kernel(
    const __hip_bfloat16* __restrict__ hbuf,
    const float* __restrict__ W2,
    __hip_bfloat16* __restrict__ qpre)      // (S*Nq, B, D)
{
    const int bid = blockIdx.x;
    const int wg = (bid & 7) * 64 + (bid >> 3);
    const int ntile = wg & 15;
    const int mtile = (wg >> 4) & 1;
    const int sq = wg >> 5;
    const int tid = threadIdx.x;
    const int lane = tid & 63;
    const int wid = tid >> 6;

    __shared__ __align__(16) unsigned short As[2][128 * 64];
    __shared__ __align__(16) unsigned short Ws[2][32 * 64];

    const char* Ag = reinterpret_cast<const char*>(hbuf + ((size_t)sq * B_ + mtile * 128) * H_);
    const float* Wb = W2 + (size_t)sq * H_ * D_ + ntile * 32;

    f32x4 acc[2][2];
    #pragma unroll
    for (int i = 0; i < 2; ++i)
        #pragma unroll
        for (int j = 0; j < 2; ++j) acc[i][j] = (f32x4){0.f, 0.f, 0.f, 0.f};

    unsigned aoff[4];
    #pragma unroll
    for (int i = 0; i < 4; ++i) {
        int row = wid * 32 + i * 8 + (lane >> 3);
        int swz = ((lane >> 3) ^ (row >> 3)) & 7;
        aoff[i] = (unsigned)row * (H_ * 2) + (((lane & 7) ^ swz) * 16);
    }
    const int wn0 = (tid & 7) * 4;
    const int wk0 = (tid >> 3) * 2;
    unsigned offW[4];
    #pragma unroll
    for (int nn = 0; nn < 4; ++nn) {
        int row = wn0 + nn;
        int swz = (row ^ (row >> 3)) & 7;
        offW[nn] = (unsigned)((row * 128 + wk0 * 2) ^ (swz << 4));
    }
    unsigned offA[2][2], offB[2][2];
    #pragma unroll
    for (int kb = 0; kb < 2; ++kb) {
        #pragma unroll
        for (int mi = 0; mi < 2; ++mi) {
            int r = wid * 32 + mi * 16 + (lane & 15);
            int swz = (r ^ (r >> 3)) & 7;
            offA[kb][mi] = r * 128 + ((((lane >> 4) + kb * 4) ^ swz) * 16);
        }
        #pragma unroll
        for (int ni = 0; ni < 2; ++ni) {
            int r = ni * 16 + (lane & 15);
            int swz = (r ^ (r >> 3)) & 7;
            offB[kb][ni] = r * 128 + ((((lane >> 4) + kb * 4) ^ swz) * 16);
        }
    }

    {
        char* dst = reinterpret_cast<char*>(&As[0][0]);
        #pragma unroll
        for (int i = 0; i < 4; ++i)
            gll16(Ag + aoff[i], dst + (wid * 32 + i * 8) * 128);
        f32x4 w0[2];
        #pragma unroll
        for (int kk = 0; kk < 2; ++kk)
            w0[kk] = ntload4(Wb + (size_t)(wk0 + kk) * D_ + wn0);
        #pragma unroll
        for (int nn = 0; nn < 4; ++nn) {
            unsigned pk = (unsigned)f2bf(w0[0][nn]) | ((unsigned)f2bf(w0[1][nn]) << 16);
            *reinterpret_cast<unsigned*>(reinterpret_cast<char*>(&Ws[0][0]) + offW[nn]) = pk;
        }
        asm volatile("s_waitcnt lgkmcnt(0)" ::: "memory");
        __builtin_amdgcn_s_barrier();
    }

    for (int kt = 0; kt < H_ / 64; ++kt) {
        const int cur = kt & 1, nxt = cur ^ 1;
        const int kn = (kt < H_ / 64 - 1) ? kt + 1 : H_ / 64 - 1;

        f32x4 wreg[2];
        {
            const float* wp = Wb + (size_t)(kn * 64 + wk0) * D_ + wn0;
            #pragma unroll
            for (int kk = 0; kk < 2; ++kk)
                wreg[kk] = ntload4(wp + (size_t)kk * D_);
        }
        {
            char* dst = reinterpret_cast<char*>(&As[nxt][0]);
            const unsigned kbyte = (unsigned)kn * 128;
            #pragma unroll
            for (int i = 0; i < 4; ++i)
                gll16(Ag + (aoff[i] + kbyte), dst + (wid * 32 + i * 8) * 128);
        }
        asm volatile("s_waitcnt vmcnt(6)" ::: "memory");
        __builtin_amdgcn_sched_barrier(0);

        const char* Al = reinterpret_cast<const char*>(&As[cur][0]);
        const char* Wl = reinterpret_cast<const char*>(&Ws[cur][0]);
        #pragma unroll
        for (int kb = 0; kb < 2; ++kb) {
            s16x8 af[2], bfr[2];
            #pragma unroll
            for (int mi = 0; mi < 2; ++mi)
                af[mi] = *reinterpret_cast<const s16x8*>(Al + offA[kb][mi]);
            #pragma unroll
            for (int ni = 0; ni < 2; ++ni)
                bfr[ni] = *reinterpret_cast<const s16x8*>(Wl + offB[kb][ni]);
            #pragma unroll
            for (int mi = 0; mi < 2; ++mi)
                #pragma unroll
                for (int ni = 0; ni < 2; ++ni)
                    acc[mi][ni] = __builtin_amdgcn_mfma_f32_16x16x32_bf16(af[mi], bfr[ni], acc[mi][ni], 0, 0, 0);
        }

        #pragma unroll
        for (int nn = 0; nn < 4; ++nn) {
            unsigned pk = (unsigned)f2bf(wreg[0][nn]) | ((unsigned)f2bf(wreg[1][nn]) << 16);
            *reinterpret_cast<unsigned*>(reinterpret_cast<char*>(&Ws[nxt][0]) + offW[nn]) = pk;
        }
        asm volatile("s_waitcnt lgkmcnt(0)" ::: "memory");
        __builtin_amdgcn_s_barrier();
    }

    #pragma unroll
    for (int mi = 0; mi < 2; ++mi)
        #pragma unroll
        for (int ni = 0; ni < 2; ++ni)
            #pragma unroll
            for (int r = 0; r < 4; ++r) {
                int row = mtile * 128 + wid * 32 + mi * 16 + ((lane >> 4) << 2) + r;
                int col = ntile * 32 + ni * 16 + (lane & 15);
                qpre[((size_t)sq * B_ + row) * D_ + col] = __float2bfloat16(acc[mi][ni][r]);
            }
}

// ---------------- kernel 6: +b2, LayerNorm over D, transposed write ----------------
__global__ __launch_bounds__(256) void lnout_kernel(
    const __hip_bfloat16* __restrict__ qpre,
    const float* __restrict__ b2,
    const float* __restrict__ lng,
    const float* __restrict__ lnb,
    float* __restrict__ out)          // (S,B,Nq,D)
{
    const int idx = blockIdx.x;
    const int sq = idx >> 8;
    const int b = idx & 255;
    const int tid = threadIdx.x;
    __shared__ float red[8];

    float v[2];
    #pragma unroll
    for (int k = 0; k < 2; ++k) {
        int d = tid + k * 256;
        v[k] = __bfloat162float(qpre[(size_t)idx * D_ + d]) + b2[sq * D_ + d];
    }
    float sum = block_sum256(v[0] + v[1], red);
    float sq2 = block_sum256(v[0] * v[0] + v[1] * v[1], red);
    float mu = sum / D_;
    float var = sq2 / D_ - mu * mu;
    float rinv = rsqrtf(var + 1e-5f);
    const int s = sq >> 2, q = sq & 3;
    #pragma unroll
    for (int k = 0; k < 2; ++k) {
        int d = tid + k * 256;
        float o = (v[k] - mu) * rinv * lng[sq * D_ + d] + lnb[sq * D_ + d];
        out[(((size_t)s * B_ + b) * NQ_ + q) * D_ + d] = o;
    }
}

extern "C" void kernel_launch(void* const* d_in, const int* in_sizes, int n_in,
                              void* d_out, int out_size, void* d_ws, size_t ws_size,
                              hipStream_t stream) {
    const float* ns_tokens   = (const float*)d_in[0];
    const float* seq_tokens  = (const float*)d_in[1];
    const unsigned char* masks = (const unsigned char*)d_in[2];
    const float* seq_stats   = (const float*)d_in[3];
    const float* gin_gamma   = (const float*)d_in[4];
    const float* gin_beta    = (const float*)d_in[5];
    const float* stat_W      = (const float*)d_in[6];
    const float* stat_b      = (const float*)d_in[7];
    const float* stat_ln_g   = (const float*)d_in[8];
    const float* stat_ln_b   = (const float*)d_in[9];
    const float* W1          = (const float*)d_in[10];
    const float* b1          = (const float*)d_in[11];
    const float* W2          = (const float*)d_in[12];
    const float* b2          = (const float*)d_in[13];
    const float* ln_g        = (const float*)d_in[14];
    const float* ln_b        = (const float*)d_in[15];
    float* out = (float*)d_out;

    // ws layout (bytes):
    // qpre 0 (4.2MB) | pooled 4194304 (2MB) | A_ns 6291456 (1MB) | nssum 7340032 (64K)
    // musig 7405568 (64K) | uprime 7471104 (128K) | usec 7602176 (128K)
    // gi_tail 7733248 (2MB) | P 9830400 (33.5MB) | h 43384832 (16.8MB)  => ~60 MB
    char* ws = (char*)d_ws;
    __hip_bfloat16* qpre    = (__hip_bfloat16*)(ws);
    float* pooled           = (float*)(ws + 4194304);
    __hip_bfloat16* A_ns    = (__hip_bfloat16*)(ws + 6291456);
    float* nssum            = (float*)(ws + 7340032);
    float* musig            = (float*)(ws + 7405568);
    float* uprime           = (float*)(ws + 7471104);
    float* usec             = (float*)(ws + 7602176);
    __hip_bfloat16* gi_tail = (__hip_bfloat16*)(ws + 7733248);
    float* Pbuf             = (float*)(ws + 9830400);
    __hip_bfloat16* hbuf    = (__hip_bfloat16*)(ws + 43384832);

    prep_kernel<<<dim3(B_), dim3(256), 0, stream>>>(ns_tokens, gin_gamma, A_ns, nssum);
    mega_kernel<<<dim3(1536), dim3(256), 0, stream>>>(
        seq_tokens, masks, A_ns, W1, gin_gamma, gin_beta, pooled, Pbuf, uprime, usec);
    tailprep_kernel<<<dim3(S_ * B_), dim3(256), 0, stream>>>(
        seq_stats, stat_W, stat_b, stat_ln_g, stat_ln_b, gin_gamma, gin_beta,
        pooled, nssum, musig, gi_tail);
    tailgemm_kernel<<<dim3(512), dim3(256), 0, stream>>>(
        gi_tail, W1, b1, Pbuf, uprime, usec, musig, hbuf);
    gemm2_kernel<<<dim3(512), dim3(256), 0, stream>>>(hbuf, W2, qpre);
    lnout_kernel<<<dim3(S_ * NQ_ * B_), dim3(256), 0, stream>>>(qpre, b2, ln_g, ln_b, out);
}

// Round 14
// 262.739 us; speedup vs baseline: 1.3903x; 1.3903x over previous
//
#include <hip/hip_runtime.h>
#include <hip/hip_bf16.h>

#define S_ 4
#define B_ 256
#define L_ 256
#define D_ 512
#define NQ_ 4
#define H_ 2048
#define G_ 3072

typedef __attribute__((ext_vector_type(4))) float f32x4;
typedef __attribute__((ext_vector_type(8))) short s16x8;

__device__ __forceinline__ unsigned short f2bf(float x) {
    __hip_bfloat16 hb = __float2bfloat16(x);
    return reinterpret_cast<unsigned short&>(hb);
}

// nontemporal f32x4 load: W streams have zero reuse -> don't let them evict L2-resident A
__device__ __forceinline__ f32x4 ntload4(const float* p) {
    return __builtin_nontemporal_load(reinterpret_cast<const f32x4*>(p));
}

// async global->LDS, 16B per lane, LDS dest = wave-uniform base + lane*16
__device__ __forceinline__ void gll16(const void* g, void* l) {
    __builtin_amdgcn_global_load_lds(
        (const __attribute__((address_space(1))) unsigned int*)g,
        (__attribute__((address_space(3))) unsigned int*)l, 16, 0, 0);
}

// block-wide sum for 256-thread blocks; red is __shared__ float[8]
__device__ __forceinline__ float block_sum256(float v, float* red) {
    #pragma unroll
    for (int off = 32; off > 0; off >>= 1) v += __shfl_down(v, off, 64);
    int tid = threadIdx.x;
    int lane = tid & 63, wid = tid >> 6;
    if (lane == 0) red[wid] = v;
    __syncthreads();
    float r = (tid < 4) ? red[tid] : 0.f;
    #pragma unroll
    for (int off = 4; off > 0; off >>= 1) r += __shfl_down(r, off, 64);
    if (tid == 0) red[0] = r;
    __syncthreads();
    float out = red[0];
    __syncthreads();
    return out;
}

// ---------------- kernel 1: masked mean pool over L ----------------
__global__ __launch_bounds__(256) void pool_kernel(
    const float* __restrict__ seq_tokens,
    const unsigned char* __restrict__ masks_raw,
    float* __restrict__ pooled)                // (S,B,D)
{
    const int sb = blockIdx.x;
    const int tid = threadIdx.x;
    __shared__ float sval[L_];
    __shared__ float scount[4];
    __shared__ f32x4 spart[256];
    __shared__ int is_bool_flag;

    if (tid == 0) is_bool_flag = 0;
    __syncthreads();
    {
        unsigned int w = reinterpret_cast<const unsigned int*>(masks_raw)[tid];
        if (w & 0xFFFFFF00u) is_bool_flag = 1;   // benign race, same value
    }
    __syncthreads();
    const bool is_bool = (is_bool_flag != 0);

    int mval;
    if (is_bool) mval = masks_raw[(size_t)sb * L_ + tid];
    else         mval = reinterpret_cast<const int*>(masks_raw)[(size_t)sb * L_ + tid];
    float valid = mval ? 0.f : 1.f;
    sval[tid] = valid;
    float c = valid;
    #pragma unroll
    for (int off = 32; off > 0; off >>= 1) c += __shfl_down(c, off, 64);
    if ((tid & 63) == 0) scount[tid >> 6] = c;
    __syncthreads();
    const float denom = fmaxf(scount[0] + scount[1] + scount[2] + scount[3], 1.f);

    const float* base = seq_tokens + (size_t)sb * L_ * D_;
    const int cidx = tid & 127;
    const int rg = tid >> 7;
    f32x4 acc = {0.f, 0.f, 0.f, 0.f};
    for (int l = rg; l < L_; l += 2) {
        float vl = sval[l];
        f32x4 v = *reinterpret_cast<const f32x4*>(base + (size_t)l * D_ + cidx * 4);
        acc += v * vl;
    }
    spart[tid] = acc;
    __syncthreads();
    if (tid < 128) {
        f32x4 r = spart[tid] + spart[tid + 128];
        r *= (1.f / denom);
        *reinterpret_cast<f32x4*>(pooled + (size_t)sb * D_ + cidx * 4) = r;
    }
}

// ---------------- kernel 2: stat proj + LN, concat, group LN -> gi (bf16) ---------
__global__ __launch_bounds__(256) void gi_kernel(
    const float* __restrict__ ns_tokens,    // (B, 2048)
    const float* __restrict__ seq_stats,    // (S,B,6)
    const float* __restrict__ stat_W,       // (S,6,D)
    const float* __restrict__ stat_b,       // (S,D)
    const float* __restrict__ stat_ln_g,
    const float* __restrict__ stat_ln_b,
    const float* __restrict__ gin_gamma,    // (G)
    const float* __restrict__ gin_beta,
    const float* __restrict__ pooled,       // (S,B,D)
    __hip_bfloat16* __restrict__ gi)        // (S,B,G)
{
    const int sb = blockIdx.x;
    const int s = sb >> 8;
    const int b = sb & 255;
    const int tid = threadIdx.x;
    __shared__ float red[8];
    __shared__ float sstat[D_];

    float st[6];
    #pragma unroll
    for (int f = 0; f < 6; ++f) st[f] = seq_stats[(size_t)sb * 6 + f];

    float sp[2];
    #pragma unroll
    for (int k = 0; k < 2; ++k) {
        int d = tid + k * 256;
        float a = stat_b[s * D_ + d];
        #pragma unroll
        for (int f = 0; f < 6; ++f) a += st[f] * stat_W[(s * 6 + f) * D_ + d];
        sp[k] = a;
    }
    float ssum = block_sum256(sp[0] + sp[1], red);
    float ssq  = block_sum256(sp[0] * sp[0] + sp[1] * sp[1], red);
    float mu = ssum / D_;
    float var = ssq / D_ - mu * mu;
    float rinv = rsqrtf(var + 1e-5f);
    #pragma unroll
    for (int k = 0; k < 2; ++k) {
        int d = tid + k * 256;
        sstat[d] = (sp[k] - mu) * rinv * stat_ln_g[s * D_ + d] + stat_ln_b[s * D_ + d];
    }
    __syncthreads();

    float gv[12];
    float gsum = 0.f, gsq = 0.f;
    #pragma unroll
    for (int k = 0; k < 12; ++k) {
        int g = tid + k * 256;
        float v;
        if (g < 2048)       v = ns_tokens[(size_t)b * 2048 + g];
        else if (g < 2560)  v = pooled[(size_t)sb * D_ + (g - 2048)];
        else                v = sstat[g - 2560];
        gv[k] = v;
        gsum += v;
        gsq += v * v;
    }
    gsum = block_sum256(gsum, red);
    gsq  = block_sum256(gsq, red);
    mu = gsum / G_;
    var = gsq / G_ - mu * mu;
    rinv = rsqrtf(var + 1e-5f);
    #pragma unroll
    for (int k = 0; k < 12; ++k) {
        int g = tid + k * 256;
        float o = (gv[k] - mu) * rinv * gin_gamma[g] + gin_beta[g];
        gi[(size_t)sb * G_ + g] = __float2bfloat16(o);
    }
}

// ---------------- kernel 3: GEMM1 -- counted-vmcnt pipeline + nontemporal W loads ----------
__global__ __launch_bounds__(256) void gemm1_kernel(
    const __hip_bfloat16* __restrict__ gi,
    const float* __restrict__ W1,
    const float* __restrict__ b1,
    __hip_bfloat16* __restrict__ hbuf)      // (S*Nq, B, H)
{
    const int bid = blockIdx.x;
    const int wg = (bid & 7) * 64 + (bid >> 3);
    const int ntile = wg & 31;      // 0..31
    const int sq = wg >> 5;         // 0..15
    const int s = sq >> 2;
    const int tid = threadIdx.x;
    const int lane = tid & 63;
    const int wid = tid >> 6;       // 0..3 (wave m-block)

    __shared__ __align__(16) unsigned short As[2][256 * 64];
    __shared__ __align__(16) unsigned short Ws[2][64 * 64];

    const char* Ag = reinterpret_cast<const char*>(gi + (size_t)s * B_ * G_);
    const float* Wb = W1 + (size_t)sq * G_ * H_ + ntile * 64;

    f32x4 acc[4][4];
    #pragma unroll
    for (int i = 0; i < 4; ++i)
        #pragma unroll
        for (int j = 0; j < 4; ++j) acc[i][j] = (f32x4){0.f, 0.f, 0.f, 0.f};

    unsigned aoff[8];
    #pragma unroll
    for (int i = 0; i < 8; ++i) {
        int row = wid * 64 + i * 8 + (lane >> 3);
        int swz = ((lane >> 3) ^ i) & 7;
        aoff[i] = (unsigned)row * (G_ * 2) + (((lane & 7) ^ swz) * 16);
    }

    const int wn0 = (tid & 15) * 4;
    const int wk0 = (tid >> 4) * 4;
    unsigned offW[4];
    #pragma unroll
    for (int nn = 0; nn < 4; ++nn) {
        int row = wn0 + nn;
        int swz = (row ^ (row >> 3)) & 7;
        offW[nn] = (unsigned)((row * 128 + wk0 * 2) ^ (swz << 4));
    }

    unsigned offA[2][4], offB[2][4];
    #pragma unroll
    for (int kb = 0; kb < 2; ++kb) {
        #pragma unroll
        for (int mi = 0; mi < 4; ++mi) {
            int r = wid * 64 + mi * 16 + (lane & 15);
            int swz = (r ^ (r >> 3)) & 7;
            offA[kb][mi] = r * 128 + ((((lane >> 4) + kb * 4) ^ swz) * 16);
        }
        #pragma unroll
        for (int ni = 0; ni < 4; ++ni) {
            int r = ni * 16 + (lane & 15);
            int swz = (r ^ (r >> 3)) & 7;
            offB[kb][ni] = r * 128 + ((((lane >> 4) + kb * 4) ^ swz) * 16);
        }
    }

    // ---- prologue
    {
        char* dst = reinterpret_cast<char*>(&As[0][0]);
        #pragma unroll
        for (int i = 0; i < 8; ++i)
            gll16(Ag + aoff[i], dst + (wid * 64 + i * 8) * 128);
        f32x4 w0[4];
        #pragma unroll
        for (int kk = 0; kk < 4; ++kk)
            w0[kk] = ntload4(Wb + (size_t)(wk0 + kk) * H_ + wn0);
        #pragma unroll
        for (int nn = 0; nn < 4; ++nn) {
            unsigned long long pk =
                (unsigned long long)f2bf(w0[0][nn]) |
                ((unsigned long long)f2bf(w0[1][nn]) << 16) |
                ((unsigned long long)f2bf(w0[2][nn]) << 32) |
                ((unsigned long long)f2bf(w0[3][nn]) << 48);
            *reinterpret_cast<unsigned long long*>(reinterpret_cast<char*>(&Ws[0][0]) + offW[nn]) = pk;
        }
        asm volatile("s_waitcnt lgkmcnt(0)" ::: "memory");
        __builtin_amdgcn_s_barrier();
    }

    // ---- main loop: 48 K-steps, one barrier each, vmcnt never drained
    for (int kt = 0; kt < G_ / 64; ++kt) {
        const int cur = kt & 1, nxt = cur ^ 1;
        const int kn = (kt < G_ / 64 - 1) ? kt + 1 : G_ / 64 - 1;

        f32x4 wreg[4];
        {
            const float* wp = Wb + (size_t)(kn * 64 + wk0) * H_ + wn0;
            #pragma unroll
            for (int kk = 0; kk < 4; ++kk)
                wreg[kk] = ntload4(wp + (size_t)kk * H_);
        }
        {
            char* dst = reinterpret_cast<char*>(&As[nxt][0]);
            const unsigned kbyte = (unsigned)kn * 128;
            #pragma unroll
            for (int i = 0; i < 8; ++i)
                gll16(Ag + (aoff[i] + kbyte), dst + (wid * 64 + i * 8) * 128);
        }
        asm volatile("s_waitcnt vmcnt(12)" ::: "memory");
        __builtin_amdgcn_sched_barrier(0);

        const char* Al = reinterpret_cast<const char*>(&As[cur][0]);
        const char* Wl = reinterpret_cast<const char*>(&Ws[cur][0]);
        #pragma unroll
        for (int kb = 0; kb < 2; ++kb) {
            s16x8 af[4], bfr[4];
            #pragma unroll
            for (int mi = 0; mi < 4; ++mi)
                af[mi] = *reinterpret_cast<const s16x8*>(Al + offA[kb][mi]);
            #pragma unroll
            for (int ni = 0; ni < 4; ++ni)
                bfr[ni] = *reinterpret_cast<const s16x8*>(Wl + offB[kb][ni]);
            #pragma unroll
            for (int mi = 0; mi < 4; ++mi)
                #pragma unroll
                for (int ni = 0; ni < 4; ++ni)
                    acc[mi][ni] = __builtin_amdgcn_mfma_f32_16x16x32_bf16(af[mi], bfr[ni], acc[mi][ni], 0, 0, 0);
        }

        #pragma unroll
        for (int nn = 0; nn < 4; ++nn) {
            unsigned long long pk =
                (unsigned long long)f2bf(wreg[0][nn]) |
                ((unsigned long long)f2bf(wreg[1][nn]) << 16) |
                ((unsigned long long)f2bf(wreg[2][nn]) << 32) |
                ((unsigned long long)f2bf(wreg[3][nn]) << 48);
            *reinterpret_cast<unsigned long long*>(reinterpret_cast<char*>(&Ws[nxt][0]) + offW[nn]) = pk;
        }
        asm volatile("s_waitcnt lgkmcnt(0)" ::: "memory");
        __builtin_amdgcn_s_barrier();
    }

    // ---- epilogue: + b1, silu, bf16 store
    const float* b1p = b1 + (size_t)sq * H_ + ntile * 64;
    __hip_bfloat16* hp = hbuf + (size_t)sq * B_ * H_;
    #pragma unroll
    for (int mi = 0; mi < 4; ++mi)
        #pragma unroll
        for (int ni = 0; ni < 4; ++ni)
            #pragma unroll
            for (int r = 0; r < 4; ++r) {
                int row = wid * 64 + mi * 16 + ((lane >> 4) << 2) + r;
                int coll = ni * 16 + (lane & 15);
                float x = acc[mi][ni][r] + b1p[coll];
                float sg = 1.f / (1.f + __expf(-x));
                hp[(size_t)row * H_ + ntile * 64 + coll] = __float2bfloat16(x * sg);
            }
}

// ---------------- kernel 4: GEMM2 -- counted-vmcnt + nontemporal W2 loads ----------------
__global__ __launch_bounds__(256, 4) void gemm2_kernel(
    const __hip_bfloat16* __restrict__ hbuf,
    const float* __restrict__ W2,
    __hip_bfloat16* __restrict__ qpre)      // (S*Nq, B, D)
{
    const int bid = blockIdx.x;
    const int wg = (bid & 7) * 64 + (bid >> 3);
    const int ntile = wg & 15;          // 0..15 (32-col tile)
    const int mtile = (wg >> 4) & 1;    // 0..1  (128-row tile)
    const int sq = wg >> 5;             // 0..15
    const int tid = threadIdx.x;
    const int lane = tid & 63;
    const int wid = tid >> 6;           // wave owns rows wid*32..+31

    __shared__ __align__(16) unsigned short As[2][128 * 64];   // 2 x 16 KB
    __shared__ __align__(16) unsigned short Ws[2][32 * 64];    // 2 x 4 KB

    const char* Ag = reinterpret_cast<const char*>(hbuf + ((size_t)sq * B_ + mtile * 128) * H_);
    const float* Wb = W2 + (size_t)sq * H_ * D_ + ntile * 32;

    f32x4 acc[2][2];
    #pragma unroll
    for (int i = 0; i < 2; ++i)
        #pragma unroll
        for (int j = 0; j < 2; ++j) acc[i][j] = (f32x4){0.f, 0.f, 0.f, 0.f};

    unsigned aoff[4];
    #pragma unroll
    for (int i = 0; i < 4; ++i) {
        int row = wid * 32 + i * 8 + (lane >> 3);
        int swz = ((lane >> 3) ^ (row >> 3)) & 7;
        aoff[i] = (unsigned)row * (H_ * 2) + (((lane & 7) ^ swz) * 16);
    }

    const int wn0 = (tid & 7) * 4;
    const int wk0 = (tid >> 3) * 2;
    unsigned offW[4];
    #pragma unroll
    for (int nn = 0; nn < 4; ++nn) {
        int row = wn0 + nn;
        int swz = (row ^ (row >> 3)) & 7;
        offW[nn] = (unsigned)((row * 128 + wk0 * 2) ^ (swz << 4));
    }

    unsigned offA[2][2], offB[2][2];
    #pragma unroll
    for (int kb = 0; kb < 2; ++kb) {
        #pragma unroll
        for (int mi = 0; mi < 2; ++mi) {
            int r = wid * 32 + mi * 16 + (lane & 15);
            int swz = (r ^ (r >> 3)) & 7;
            offA[kb][mi] = r * 128 + ((((lane >> 4) + kb * 4) ^ swz) * 16);
        }
        #pragma unroll
        for (int ni = 0; ni < 2; ++ni) {
            int r = ni * 16 + (lane & 15);
            int swz = (r ^ (r >> 3)) & 7;
            offB[kb][ni] = r * 128 + ((((lane >> 4) + kb * 4) ^ swz) * 16);
        }
    }

    // ---- prologue: gll A(0); load+pack W(0) -> Ws[0]
    {
        char* dst = reinterpret_cast<char*>(&As[0][0]);
        #pragma unroll
        for (int i = 0; i < 4; ++i)
            gll16(Ag + aoff[i], dst + (wid * 32 + i * 8) * 128);
        f32x4 w0[2];
        #pragma unroll
        for (int kk = 0; kk < 2; ++kk)
            w0[kk] = ntload4(Wb + (size_t)(wk0 + kk) * D_ + wn0);
        #pragma unroll
        for (int nn = 0; nn < 4; ++nn) {
            unsigned pk = (unsigned)f2bf(w0[0][nn]) | ((unsigned)f2bf(w0[1][nn]) << 16);
            *reinterpret_cast<unsigned*>(reinterpret_cast<char*>(&Ws[0][0]) + offW[nn]) = pk;
        }
        asm volatile("s_waitcnt lgkmcnt(0)" ::: "memory");
        __builtin_amdgcn_s_barrier();
    }

    // ---- main loop: 32 K-steps, one barrier each, vmcnt never drained
    for (int kt = 0; kt < H_ / 64; ++kt) {
        const int cur = kt & 1, nxt = cur ^ 1;
        const int kn = (kt < H_ / 64 - 1) ? kt + 1 : H_ / 64 - 1;

        f32x4 wreg[2];
        {
            const float* wp = Wb + (size_t)(kn * 64 + wk0) * D_ + wn0;
            #pragma unroll
            for (int kk = 0; kk < 2; ++kk)
                wreg[kk] = ntload4(wp + (size_t)kk * D_);
        }
        {
            char* dst = reinterpret_cast<char*>(&As[nxt][0]);
            const unsigned kbyte = (unsigned)kn * 128;
            #pragma unroll
            for (int i = 0; i < 4; ++i)
                gll16(Ag + (aoff[i] + kbyte), dst + (wid * 32 + i * 8) * 128);
        }
        asm volatile("s_waitcnt vmcnt(6)" ::: "memory");
        __builtin_amdgcn_sched_barrier(0);

        const char* Al = reinterpret_cast<const char*>(&As[cur][0]);
        const char* Wl = reinterpret_cast<const char*>(&Ws[cur][0]);
        #pragma unroll
        for (int kb = 0; kb < 2; ++kb) {
            s16x8 af[2], bfr[2];
            #pragma unroll
            for (int mi = 0; mi < 2; ++mi)
                af[mi] = *reinterpret_cast<const s16x8*>(Al + offA[kb][mi]);
            #pragma unroll
            for (int ni = 0; ni < 2; ++ni)
                bfr[ni] = *reinterpret_cast<const s16x8*>(Wl + offB[kb][ni]);
            #pragma unroll
            for (int mi = 0; mi < 2; ++mi)
                #pragma unroll
                for (int ni = 0; ni < 2; ++ni)
                    acc[mi][ni] = __builtin_amdgcn_mfma_f32_16x16x32_bf16(af[mi], bfr[ni], acc[mi][ni], 0, 0, 0);
        }

        #pragma unroll
        for (int nn = 0; nn < 4; ++nn) {
            unsigned pk = (unsigned)f2bf(wreg[0][nn]) | ((unsigned)f2bf(wreg[1][nn]) << 16);
            *reinterpret_cast<unsigned*>(reinterpret_cast<char*>(&Ws[nxt][0]) + offW[nn]) = pk;
        }
        asm volatile("s_waitcnt lgkmcnt(0)" ::: "memory");
        __builtin_amdgcn_s_barrier();
    }

    // ---- epilogue: bf16 store
    #pragma unroll
    for (int mi = 0; mi < 2; ++mi)
        #pragma unroll
        for (int ni = 0; ni < 2; ++ni)
            #pragma unroll
            for (int r = 0; r < 4; ++r) {
                int row = mtile * 128 + wid * 32 + mi * 16 + ((lane >> 4) << 2) + r;
                int col = ntile * 32 + ni * 16 + (lane & 15);
                qpre[((size_t)sq * B_ + row) * D_ + col] = __float2bfloat16(acc[mi][ni][r]);
            }
}

// ---------------- kernel 5: +b2, LayerNorm over D, transposed write ----------------
__global__ __launch_bounds__(256) void lnout_kernel(
    const __hip_bfloat16* __restrict__ qpre,   // (S*Nq, B, D) bf16
    const float* __restrict__ b2,
    const float* __restrict__ lng,
    const float* __restrict__ lnb,
    float* __restrict__ out)          // (S,B,Nq,D)
{
    const int idx = blockIdx.x;       // sq*B + b
    const int sq = idx >> 8;
    const int b = idx & 255;
    const int tid = threadIdx.x;
    __shared__ float red[8];

    float v[2];
    #pragma unroll
    for (int k = 0; k < 2; ++k) {
        int d = tid + k * 256;
        v[k] = __bfloat162float(qpre[(size_t)idx * D_ + d]) + b2[sq * D_ + d];
    }
    float sum = block_sum256(v[0] + v[1], red);
    float sq2 = block_sum256(v[0] * v[0] + v[1] * v[1], red);
    float mu = sum / D_;
    float var = sq2 / D_ - mu * mu;
    float rinv = rsqrtf(var + 1e-5f);
    const int s = sq >> 2, q = sq & 3;
    #pragma unroll
    for (int k = 0; k < 2; ++k) {
        int d = tid + k * 256;
        float o = (v[k] - mu) * rinv * lng[sq * D_ + d] + lnb[sq * D_ + d];
        out[(((size_t)s * B_ + b) * NQ_ + q) * D_ + d] = o;
    }
}

extern "C" void kernel_launch(void* const* d_in, const int* in_sizes, int n_in,
                              void* d_out, int out_size, void* d_ws, size_t ws_size,
                              hipStream_t stream) {
    const float* ns_tokens   = (const float*)d_in[0];
    const float* seq_tokens  = (const float*)d_in[1];
    const unsigned char* masks = (const unsigned char*)d_in[2];
    const float* seq_stats   = (const float*)d_in[3];
    const float* gin_gamma   = (const float*)d_in[4];
    const float* gin_beta    = (const float*)d_in[5];
    const float* stat_W      = (const float*)d_in[6];
    const float* stat_b      = (const float*)d_in[7];
    const float* stat_ln_g   = (const float*)d_in[8];
    const float* stat_ln_b   = (const float*)d_in[9];
    const float* W1          = (const float*)d_in[10];
    const float* b1          = (const float*)d_in[11];
    const float* W2          = (const float*)d_in[12];
    const float* b2          = (const float*)d_in[13];
    const float* ln_g        = (const float*)d_in[14];
    const float* ln_b        = (const float*)d_in[15];
    float* out = (float*)d_out;

    // ws layout: pooled f32 2 MB | gi bf16 6 MB | h bf16 16.8 MB | qpre bf16 4.2 MB
    char* ws = (char*)d_ws;
    float* pooled        = (float*)(ws);
    __hip_bfloat16* gi   = (__hip_bfloat16*)(ws + 2097152);
    __hip_bfloat16* hbuf = (__hip_bfloat16*)(ws + 2097152 + 6291456);
    __hip_bfloat16* qpre = (__hip_bfloat16*)(ws + 2097152 + 6291456 + 16777216);

    pool_kernel<<<dim3(S_ * B_), dim3(256), 0, stream>>>(seq_tokens, masks, pooled);
    gi_kernel<<<dim3(S_ * B_), dim3(256), 0, stream>>>(ns_tokens, seq_stats, stat_W, stat_b,
                                                       stat_ln_g, stat_ln_b, gin_gamma, gin_beta,
                                                       pooled, gi);
    gemm1_kernel<<<dim3(32 * S_ * NQ_), dim3(256), 0, stream>>>(gi, W1, b1, hbuf);
    gemm2_kernel<<<dim3(512), dim3(256), 0, stream>>>(hbuf, W2, qpre);
    lnout_kernel<<<dim3(S_ * NQ_ * B_), dim3(256), 0, stream>>>(qpre, b2, ln_g, ln_b, out);
}